// Round 11
// baseline (395.941 us; speedup 1.0000x reference)
//
#include <hip/hip_runtime.h>
#include <hip/hip_bf16.h>
#include <math.h>

#define D 128
#define LRELU_SLOPE 0.2f
#define BSH 9
#define BSZ 512
#define BCAP 10240
#define SC_CHUNK 16384

typedef __attribute__((ext_vector_type(8))) short bf16x8;
typedef __attribute__((ext_vector_type(4))) float f32x4;

__device__ __forceinline__ float lrelu(float x){ return x > 0.f ? x : LRELU_SLOPE * x; }

__device__ __forceinline__ unsigned short bf16_rn(float x){
  unsigned int u = __float_as_uint(x);
  return (unsigned short)((u + 0x7FFFu + ((u >> 16) & 1u)) >> 16);
}
__device__ __forceinline__ float bf16_lo_f(unsigned int u){ return __uint_as_float(u << 16); }
__device__ __forceinline__ float bf16_hi_f(unsigned int u){ return __uint_as_float(u & 0xFFFF0000u); }

// monotone float<->uint encoding for atomicMax on possibly-negative floats
__device__ __forceinline__ unsigned int enc_f(float f){
  unsigned int u = __float_as_uint(f);
  return (u & 0x80000000u) ? ~u : (u | 0x80000000u);
}
__device__ __forceinline__ float dec_f(unsigned int e){
  return __uint_as_float((e & 0x80000000u) ? (e & 0x7FFFFFFFu) : ~e);
}

// ---------------- edge scatter into fixed-stride buckets ----------------
// bcur pre-initialized to b*BCAP (in wafrag_kernel). packed = (src<<9)|(dst&511).
__global__ __launch_bounds__(1024) void bucket_scatter_kernel(const int* __restrict__ src,
    const int* __restrict__ dst, int E, int* __restrict__ bcur,
    unsigned int* __restrict__ ebuf, int nbuck){
  __shared__ int h[256];
  __shared__ int cb[256];
  int t = threadIdx.x;
  int base = blockIdx.x * SC_CHUNK;
  int end = base + SC_CHUNK; if (end > E) end = E;
  if (t < 256) h[t] = 0;
  __syncthreads();
  for (int e = base + t; e < end; e += 1024)
    atomicAdd(&h[dst[e] >> BSH], 1);
  __syncthreads();
  if (t < nbuck){
    cb[t] = h[t] ? atomicAdd(&bcur[t], h[t]) : 0;   // absolute reservation
    h[t] = 0;                                        // reuse as local cursor
  }
  __syncthreads();
  for (int e = base + t; e < end; e += 1024){
    int d = dst[e];
    int b = d >> BSH;
    int lpos = atomicAdd(&h[b], 1);
    ebuf[cb[b] + lpos] = ((unsigned int)src[e] << BSH) | (unsigned int)(d & (BSZ-1));
  }
}

// One block per bucket: LDS count[512] -> scan -> per-node (beg,end) + col scatter
// within the bucket's strided window.
__global__ __launch_bounds__(256) void bucket_csr_kernel(const unsigned int* __restrict__ ebuf,
    const int* __restrict__ bcur, int2* __restrict__ rowrange, int* __restrict__ colb,
    int n, int nbuck){
  __shared__ int c[512];
  __shared__ int ps[256];
  int b = blockIdx.x;
  int t = threadIdx.x;
  int base = b * BCAP;
  int end  = bcur[b];
  c[t] = 0; c[t+256] = 0;
  __syncthreads();
  for (int i = base + t; i < end; i += 256)
    atomicAdd(&c[ebuf[i] & (BSZ-1)], 1);
  __syncthreads();
  int a0 = c[2*t], a1 = c[2*t+1];
  int pair = a0 + a1;
  ps[t] = pair;
  __syncthreads();
  #pragma unroll
  for (int d = 1; d < 256; d <<= 1){
    int add = (t >= d) ? ps[t-d] : 0;
    __syncthreads();
    ps[t] += add;
    __syncthreads();
  }
  int excl = ps[t] - pair;
  __syncthreads();
  int lo = b << BSH;
  int g0 = lo + 2*t, g1 = g0 + 1;
  if (g0 < n) rowrange[g0] = make_int2(base + excl,      base + excl + a0);
  if (g1 < n) rowrange[g1] = make_int2(base + excl + a0, base + excl + a0 + a1);
  c[2*t]   = excl;
  c[2*t+1] = excl + a0;
  __syncthreads();
  for (int i = base + t; i < end; i += 256){
    unsigned int p = ebuf[i];
    int dlo = p & (BSZ-1);
    int pos = base + atomicAdd(&c[dlo], 1);
    colb[pos] = (int)(p >> BSH);
  }
}

// ---------------- W pre-split into per-wave MFMA fragment layout ----------------
__global__ __launch_bounds__(256) void wsplit_kernel(const float* __restrict__ W,
    unsigned short* __restrict__ Whf, unsigned short* __restrict__ Wlf){
  int t = blockIdx.x*256 + threadIdx.x;   // 0..16383
  int k  = t >> 7;
  int nn = t & 127;
  float w = W[t];
  unsigned short h = bf16_rn(w);
  float whf = __uint_as_float(((unsigned int)h) << 16);
  unsigned short l = bf16_rn(w - whf);
  int kc = k >> 5, l4 = (k >> 3) & 3, e = k & 7;
  int cf = nn >> 4, l15 = nn & 15;
  int idx = ((kc*8 + cf)*64 + l4*16 + l15)*8 + e;
  Whf[idx] = h; Wlf[idx] = l;
}

// ---------------- Wa = W @ a ----------------
__global__ __launch_bounds__(64) void wa_kernel(const float* __restrict__ W,
    const float* __restrict__ a_src, const float* __restrict__ a_dst,
    float* __restrict__ wa_s, float* __restrict__ wa_d){
  int task = blockIdx.x;           // 0..255
  int row = task & 127;
  const float* a = (task >> 7) ? a_dst : a_src;
  int l = threadIdx.x;
  float2 v = ((const float2*)(W + row*D))[l];
  float p = v.x*a[2*l] + v.y*a[2*l+1];
  #pragma unroll
  for (int off = 32; off >= 1; off >>= 1) p += __shfl_xor(p, off);
  if (l == 0) ((task >> 7) ? wa_d : wa_s)[row] = p;
}

// ---------------- Wa -> extra B-fragment tile + init duties ----------------
// Also zeroes mx[0..1] and (layer 1 only) initializes bucket cursors.
__global__ __launch_bounds__(256) void wafrag_kernel(const float* __restrict__ wa_s,
    const float* __restrict__ wa_d, unsigned short* __restrict__ Whfx,
    unsigned short* __restrict__ Wlfx, unsigned int* __restrict__ mx,
    int* __restrict__ bcur, int nbuck){
  int t = threadIdx.x;             // 256 = kc(4) x lane(64)
  if (t < 2) mx[t] = 0u;
  if (bcur && t < nbuck) bcur[t] = t * BCAP;
  int kc = t >> 6, lane = t & 63;
  int l15 = lane & 15, l4 = lane >> 4;
  unsigned short hh[8], ll[8];
  #pragma unroll
  for (int e = 0; e < 8; ++e){
    int k = (kc*4 + l4)*8 + e;
    float v = (l15 == 0) ? wa_s[k] : ((l15 == 1) ? wa_d[k] : 0.f);
    unsigned short h = bf16_rn(v);
    hh[e] = h;
    ll[e] = bf16_rn(v - __uint_as_float(((unsigned)h) << 16));
  }
  #pragma unroll
  for (int e = 0; e < 8; ++e){ Whfx[t*8 + e] = hh[e]; Wlfx[t*8 + e] = ll[e]; }
}

// ---------------- MFMA bf16 GEMM (2-term) + MFMA logits + fused global max ----------------
// Hb stored in PERMUTED row layout: ushort p of row r holds H[r][(p&7)*16 + (p>>3)].
__global__ __launch_bounds__(256) void gemm_al_kernel(const float* __restrict__ X,
    const unsigned short* __restrict__ Whf, const unsigned short* __restrict__ Wlf,
    const unsigned short* __restrict__ Whfx, const unsigned short* __restrict__ Wlfx,
    unsigned short* __restrict__ Hb, float* __restrict__ ALs, float* __restrict__ ALd,
    unsigned int* __restrict__ mx, int n)
{
  __shared__ unsigned short Xh[128*128];   // 32 KB
  int tid  = threadIdx.x;
  int lane = tid & 63;
  int wave = tid >> 6;
  int row0 = blockIdx.x * 128;
  int c4   = tid & 31;

  #pragma unroll 4
  for (int it = 0; it < 16; ++it){
    int f  = it*256 + tid;
    int r  = f >> 5;
    float4 v = make_float4(0.f,0.f,0.f,0.f);
    int gr = row0 + r;
    if (gr < n) v = ((const float4*)(X + (size_t)gr*D))[c4];
    unsigned short h0 = bf16_rn(v.x);
    unsigned short h1 = bf16_rn(v.y);
    unsigned short h2 = bf16_rn(v.z);
    unsigned short h3 = bf16_rn(v.w);
    int g   = (c4 >> 1) ^ (r & 7);
    int idx = r*128 + (g << 3) + ((c4 & 1) << 2);
    *(uint2*)&Xh[idx] = make_uint2((unsigned)h0 | ((unsigned)h1<<16),
                                   (unsigned)h2 | ((unsigned)h3<<16));
  }
  __syncthreads();

  int l15 = lane & 15;
  int l4  = lane >> 4;

  f32x4 acc[2][8];
  f32x4 acc2[2];
  #pragma unroll
  for (int rf = 0; rf < 2; ++rf){
    #pragma unroll
    for (int cf = 0; cf < 8; ++cf)
      acc[rf][cf] = (f32x4){0.f, 0.f, 0.f, 0.f};
    acc2[rf] = (f32x4){0.f, 0.f, 0.f, 0.f};
  }

  #pragma unroll
  for (int kc = 0; kc < 4; ++kc){
    int g = kc*4 + l4;
    bf16x8 ah[2];
    #pragma unroll
    for (int rf = 0; rf < 2; ++rf){
      int r   = wave*32 + rf*16 + l15;
      int idx = r*128 + ((g ^ (r & 7)) << 3);
      ah[rf] = *(const bf16x8*)&Xh[idx];
    }
    #pragma unroll
    for (int cf = 0; cf < 8; ++cf){
      int foff = ((kc*8 + cf) << 9) + (lane << 3);
      bf16x8 bh = *(const bf16x8*)&Whf[foff];
      bf16x8 bl = *(const bf16x8*)&Wlf[foff];
      #pragma unroll
      for (int rf = 0; rf < 2; ++rf){
        acc[rf][cf] = __builtin_amdgcn_mfma_f32_16x16x32_bf16(ah[rf], bh, acc[rf][cf], 0, 0, 0);
        acc[rf][cf] = __builtin_amdgcn_mfma_f32_16x16x32_bf16(ah[rf], bl, acc[rf][cf], 0, 0, 0);
      }
    }
    {
      int foffx = ((kc << 6) + lane) << 3;
      bf16x8 bhx = *(const bf16x8*)&Whfx[foffx];
      bf16x8 blx = *(const bf16x8*)&Wlfx[foffx];
      #pragma unroll
      for (int rf = 0; rf < 2; ++rf){
        acc2[rf] = __builtin_amdgcn_mfma_f32_16x16x32_bf16(ah[rf], bhx, acc2[rf], 0, 0, 0);
        acc2[rf] = __builtin_amdgcn_mfma_f32_16x16x32_bf16(ah[rf], blx, acc2[rf], 0, 0, 0);
      }
    }
  }

  float ms = -3e38f, md = -3e38f;
  #pragma unroll
  for (int rf = 0; rf < 2; ++rf){
    #pragma unroll
    for (int reg = 0; reg < 4; ++reg){
      int gr = row0 + wave*32 + rf*16 + l4*4 + reg;   // C/D: row=(lane>>4)*4+reg
      if (gr < n){
        unsigned int p0 = (unsigned)bf16_rn(acc[rf][0][reg]) | ((unsigned)bf16_rn(acc[rf][1][reg]) << 16);
        unsigned int p1 = (unsigned)bf16_rn(acc[rf][2][reg]) | ((unsigned)bf16_rn(acc[rf][3][reg]) << 16);
        unsigned int p2 = (unsigned)bf16_rn(acc[rf][4][reg]) | ((unsigned)bf16_rn(acc[rf][5][reg]) << 16);
        unsigned int p3 = (unsigned)bf16_rn(acc[rf][6][reg]) | ((unsigned)bf16_rn(acc[rf][7][reg]) << 16);
        ((uint4*)(Hb + (size_t)gr*D))[l15] = make_uint4(p0, p1, p2, p3);
        if (l15 == 0){      ALs[gr] = acc2[rf][reg]; ms = fmaxf(ms, acc2[rf][reg]); }
        else if (l15 == 1){ ALd[gr] = acc2[rf][reg]; md = fmaxf(md, acc2[rf][reg]); }
      }
    }
  }
  // fused global max (per-wave reduce + one atomic pair)
  #pragma unroll
  for (int off = 32; off >= 1; off >>= 1){
    ms = fmaxf(ms, __shfl_xor(ms, off));
    md = fmaxf(md, __shfl_xor(md, off));
  }
  if (lane == 0){
    atomicMax(&mx[0], enc_f(ms));
    atomicMax(&mx[1], enc_f(md));
  }
}

// ---------------- fused softmax + weighted gather aggregation ----------------
// Global-bound softmax (M >= all logits). Per chunk: lane q computes w for edge
// beg+q, stages s/w to wave-private LDS (b32 arrays, conflict-free); gather loop
// reads them with uniform ds_read (broadcast). z accumulates per-lane.
__global__ __launch_bounds__(256) void agg_kernel(const unsigned short* __restrict__ Hb,
    const float* __restrict__ ALs, const float* __restrict__ ALd,
    const unsigned int* __restrict__ mx,
    const int2* __restrict__ rowrange, const int* __restrict__ colb,
    const float* __restrict__ bias, float* __restrict__ out, int n)
{
  __shared__ unsigned int sArr[256];
  __shared__ float wArr[256];
  int gtid = blockIdx.x*blockDim.x + threadIdx.x;
  int node = gtid >> 6;
  int lane = threadIdx.x & 63;
  int wbase = threadIdx.x & 192;         // wave slice base
  if (node >= n) return;

  float M = lrelu(dec_f(mx[0]) + dec_f(mx[1]));   // upper bound on all edge logits

  int2 rr = rowrange[node];
  int beg = rr.x, end = rr.y;
  float ald = ALd[node];
  float ws = __expf(lrelu(ALs[node] + ald) - M);  // self-loop weight

  const unsigned int* H2 = (const unsigned int*)Hb;
  unsigned int us = H2[(unsigned)(node*64 + lane)];
  float2 acc; acc.x = ws * bf16_lo_f(us); acc.y = ws * bf16_hi_f(us);
  float zl = 0.f;

  for (int c = beg; c < end; c += 64){
    int j = c + lane;
    bool valid = j < end;
    int s_l = valid ? colb[j] : 0;
    float w_l = valid ? __expf(lrelu(ALs[s_l] + ald) - M) : 0.f;
    zl += w_l;

    sArr[threadIdx.x] = (unsigned)s_l;
    wArr[threadIdx.x] = w_l;

    int cnt = end - c; if (cnt > 64) cnt = 64;
    int q = 0;
    for (; q + 8 <= cnt; q += 8){
      unsigned int ss[8]; float ww[8]; unsigned int u[8];
      #pragma unroll
      for (int p = 0; p < 8; ++p){ ss[p] = sArr[wbase + q + p]; ww[p] = wArr[wbase + q + p]; }
      #pragma unroll
      for (int p = 0; p < 8; ++p) u[p] = H2[(unsigned)(ss[p]*64u + lane)];
      #pragma unroll
      for (int p = 0; p < 8; ++p){
        acc.x += ww[p]*bf16_lo_f(u[p]);
        acc.y += ww[p]*bf16_hi_f(u[p]);
      }
    }
    for (; q < cnt; ++q){
      unsigned int u = H2[(unsigned)(sArr[wbase + q]*64u + lane)];
      float w = wArr[wbase + q];
      acc.x += w*bf16_lo_f(u); acc.y += w*bf16_hi_f(u);
    }
  }

  #pragma unroll
  for (int off = 32; off >= 1; off >>= 1) zl += __shfl_xor(zl, off);
  float zi = 1.f / (zl + ws);
  acc.x *= zi; acc.y *= zi;

  // permuted -> standard: lane t needs cols 2t (v0) and 2t+1 (v1)
  int q0 = (lane >> 4) + ((lane & 7) << 3);
  int q1 = q0 + 4;
  int hsel = (lane >> 3) & 1;
  float x0 = __shfl(acc.x, q0), y0 = __shfl(acc.y, q0);
  float x1 = __shfl(acc.x, q1), y1 = __shfl(acc.y, q1);
  float v0 = hsel ? y0 : x0;
  float v1 = hsel ? y1 : x1;

  float2 b2 = ((const float2*)bias)[lane];
  ((float2*)out)[(size_t)node*64 + lane] = make_float2(v0 + b2.x, v1 + b2.y);
}

// ---------------- launch ----------------
extern "C" void kernel_launch(void* const* d_in, const int* in_sizes, int n_in,
                              void* d_out, int out_size, void* d_ws, size_t ws_size,
                              hipStream_t stream)
{
  const float* x   = (const float*)d_in[0];
  const int*   ei  = (const int*)  d_in[1];
  const float* W1  = (const float*)d_in[2];
  const float* as1 = (const float*)d_in[3];
  const float* ad1 = (const float*)d_in[4];
  const float* b1  = (const float*)d_in[5];
  const float* W2  = (const float*)d_in[6];
  const float* as2 = (const float*)d_in[7];
  const float* ad2 = (const float*)d_in[8];
  const float* b2  = (const float*)d_in[9];

  int n = in_sizes[0] / D;
  int E = in_sizes[1] / 2;
  const int* src = ei;
  const int* dst = ei + E;
  int nbuck = (n + BSZ - 1) >> BSH;

  // workspace layout (256B-aligned chunks)
  char* base = (char*)d_ws;
  size_t off = 0;
  auto alloc = [&](size_t bytes) -> char* {
    char* p = base + off;
    off = (off + bytes + 255) & ~(size_t)255;
    return p;
  };
  unsigned short* hb = (unsigned short*)alloc((size_t)n*D*2);
  float* als    = (float*)alloc((size_t)n*4);
  float* ald    = (float*)alloc((size_t)n*4);
  int2* rowrange = (int2*)alloc((size_t)n*8);
  int* bcur     = (int*)alloc(256*4);
  unsigned int* mx1 = (unsigned int*)alloc(2*4);
  unsigned int* mx2 = (unsigned int*)alloc(2*4);
  unsigned short* whf1 = (unsigned short*)alloc(16384*2);
  unsigned short* wlf1 = (unsigned short*)alloc(16384*2);
  unsigned short* whf2 = (unsigned short*)alloc(16384*2);
  unsigned short* wlf2 = (unsigned short*)alloc(16384*2);
  unsigned short* whfx1 = (unsigned short*)alloc(2048*2);
  unsigned short* wlfx1 = (unsigned short*)alloc(2048*2);
  unsigned short* whfx2 = (unsigned short*)alloc(2048*2);
  unsigned short* wlfx2 = (unsigned short*)alloc(2048*2);
  float* wa_s1 = (float*)alloc(128*4);
  float* wa_d1 = (float*)alloc(128*4);
  float* wa_s2 = (float*)alloc(128*4);
  float* wa_d2 = (float*)alloc(128*4);
  unsigned int* ebuf = (unsigned int*)alloc((size_t)nbuck*BCAP*4);
  int* colb = (int*)alloc((size_t)nbuck*BCAP*4);

  float* out = (float*)d_out;

  // prep (all tiny, also perform init duties)
  wsplit_kernel<<<64, 256, 0, stream>>>(W1, whf1, wlf1);
  wsplit_kernel<<<64, 256, 0, stream>>>(W2, whf2, wlf2);
  wa_kernel    <<<256, 64, 0, stream>>>(W1, as1, ad1, wa_s1, wa_d1);
  wa_kernel    <<<256, 64, 0, stream>>>(W2, as2, ad2, wa_s2, wa_d2);
  wafrag_kernel<<<1, 256, 0, stream>>>(wa_s1, wa_d1, whfx1, wlfx1, mx1, bcur, nbuck);
  wafrag_kernel<<<1, 256, 0, stream>>>(wa_s2, wa_d2, whfx2, wlfx2, mx2, nullptr, 0);

  // CSR build
  int sc_blocks = (E + SC_CHUNK - 1) / SC_CHUNK;
  bucket_scatter_kernel<<<sc_blocks, 1024, 0, stream>>>(src, dst, E, bcur, ebuf, nbuck);
  bucket_csr_kernel    <<<nbuck, 256, 0, stream>>>(ebuf, bcur, rowrange, colb, n, nbuck);

  int ntiles = (n + 127)/128;
  int aggblocks = (int)(((size_t)n*64 + 255)/256);

  gemm_al_kernel<<<ntiles, 256, 0, stream>>>(x,  whf1, wlf1, whfx1, wlfx1, hb, als, ald, mx1, n);
  agg_kernel    <<<aggblocks, 256, 0, stream>>>(hb, als, ald, mx1, rowrange, colb, b1, out, n);
  gemm_al_kernel<<<ntiles, 256, 0, stream>>>(out, whf2, wlf2, whfx2, wlfx2, hb, als, ald, mx2, n);
  agg_kernel    <<<aggblocks, 256, 0, stream>>>(hb, als, ald, mx2, rowrange, colb, b2, out, n);
}

// Round 12
// 287.865 us; speedup vs baseline: 1.3754x; 1.3754x over previous
//
#include <hip/hip_runtime.h>
#include <hip/hip_bf16.h>
#include <math.h>

#define D 128
#define LRELU_SLOPE 0.2f
#define BSH 9
#define BSZ 512
#define BCAP 10240
#define SC_CHUNK 16384

typedef __attribute__((ext_vector_type(8))) short bf16x8;
typedef __attribute__((ext_vector_type(4))) float f32x4;

__device__ __forceinline__ float lrelu(float x){ return x > 0.f ? x : LRELU_SLOPE * x; }

__device__ __forceinline__ unsigned short bf16_rn(float x){
  unsigned int u = __float_as_uint(x);
  return (unsigned short)((u + 0x7FFFu + ((u >> 16) & 1u)) >> 16);
}
__device__ __forceinline__ float bf16_lo_f(unsigned int u){ return __uint_as_float(u << 16); }
__device__ __forceinline__ float bf16_hi_f(unsigned int u){ return __uint_as_float(u & 0xFFFF0000u); }

// monotone float<->uint encoding for atomicMax on possibly-negative floats
__device__ __forceinline__ unsigned int enc_f(float f){
  unsigned int u = __float_as_uint(f);
  return (u & 0x80000000u) ? ~u : (u | 0x80000000u);
}
__device__ __forceinline__ float dec_f(unsigned int e){
  return __uint_as_float((e & 0x80000000u) ? (e & 0x7FFFFFFFu) : ~e);
}

// ---------------- edge scatter into fixed-stride buckets ----------------
// bcur pre-initialized to b*BCAP (in wafrag_kernel). packed = (src<<9)|(dst&511).
__global__ __launch_bounds__(1024) void bucket_scatter_kernel(const int* __restrict__ src,
    const int* __restrict__ dst, int E, int* __restrict__ bcur,
    unsigned int* __restrict__ ebuf, int nbuck){
  __shared__ int h[256];
  __shared__ int cb[256];
  int t = threadIdx.x;
  int base = blockIdx.x * SC_CHUNK;
  int end = base + SC_CHUNK; if (end > E) end = E;
  if (t < 256) h[t] = 0;
  __syncthreads();
  for (int e = base + t; e < end; e += 1024)
    atomicAdd(&h[dst[e] >> BSH], 1);
  __syncthreads();
  if (t < nbuck){
    cb[t] = h[t] ? atomicAdd(&bcur[t], h[t]) : 0;   // absolute reservation
    h[t] = 0;                                        // reuse as local cursor
  }
  __syncthreads();
  for (int e = base + t; e < end; e += 1024){
    int d = dst[e];
    int b = d >> BSH;
    int lpos = atomicAdd(&h[b], 1);
    ebuf[cb[b] + lpos] = ((unsigned int)src[e] << BSH) | (unsigned int)(d & (BSZ-1));
  }
}

// One block per bucket: LDS count[512] -> scan -> per-node (beg,end) + col scatter
__global__ __launch_bounds__(256) void bucket_csr_kernel(const unsigned int* __restrict__ ebuf,
    const int* __restrict__ bcur, int2* __restrict__ rowrange, int* __restrict__ colb,
    int n, int nbuck){
  __shared__ int c[512];
  __shared__ int ps[256];
  int b = blockIdx.x;
  int t = threadIdx.x;
  int base = b * BCAP;
  int end  = bcur[b];
  c[t] = 0; c[t+256] = 0;
  __syncthreads();
  for (int i = base + t; i < end; i += 256)
    atomicAdd(&c[ebuf[i] & (BSZ-1)], 1);
  __syncthreads();
  int a0 = c[2*t], a1 = c[2*t+1];
  int pair = a0 + a1;
  ps[t] = pair;
  __syncthreads();
  #pragma unroll
  for (int d = 1; d < 256; d <<= 1){
    int add = (t >= d) ? ps[t-d] : 0;
    __syncthreads();
    ps[t] += add;
    __syncthreads();
  }
  int excl = ps[t] - pair;
  __syncthreads();
  int lo = b << BSH;
  int g0 = lo + 2*t, g1 = g0 + 1;
  if (g0 < n) rowrange[g0] = make_int2(base + excl,      base + excl + a0);
  if (g1 < n) rowrange[g1] = make_int2(base + excl + a0, base + excl + a0 + a1);
  c[2*t]   = excl;
  c[2*t+1] = excl + a0;
  __syncthreads();
  for (int i = base + t; i < end; i += 256){
    unsigned int p = ebuf[i];
    int dlo = p & (BSZ-1);
    int pos = base + atomicAdd(&c[dlo], 1);
    colb[pos] = (int)(p >> BSH);
  }
}

// ---------------- W pre-split (both layers in one launch) ----------------
__global__ __launch_bounds__(256) void wsplit_kernel(const float* __restrict__ W1,
    const float* __restrict__ W2,
    unsigned short* __restrict__ Whf1, unsigned short* __restrict__ Wlf1,
    unsigned short* __restrict__ Whf2, unsigned short* __restrict__ Wlf2){
  int b = blockIdx.x;
  const float* W = (b >= 64) ? W2 : W1;
  unsigned short* Whf = (b >= 64) ? Whf2 : Whf1;
  unsigned short* Wlf = (b >= 64) ? Wlf2 : Wlf1;
  int t = (b & 63)*256 + threadIdx.x;   // 0..16383
  int k  = t >> 7;
  int nn = t & 127;
  float w = W[t];
  unsigned short h = bf16_rn(w);
  float whf = __uint_as_float(((unsigned int)h) << 16);
  unsigned short l = bf16_rn(w - whf);
  int kc = k >> 5, l4 = (k >> 3) & 3, e = k & 7;
  int cf = nn >> 4, l15 = nn & 15;
  int idx = ((kc*8 + cf)*64 + l4*16 + l15)*8 + e;
  Whf[idx] = h; Wlf[idx] = l;
}

// ---------------- Wa dots + extra B-fragment tile + init duties (both layers) ----------------
// Block 0 = layer 1 (also inits bcur), block 1 = layer 2. Each block also zeroes its mx pair.
__global__ __launch_bounds__(256) void wafrag_kernel(const float* __restrict__ W1,
    const float* __restrict__ W2,
    const float* __restrict__ as1, const float* __restrict__ ad1,
    const float* __restrict__ as2, const float* __restrict__ ad2,
    unsigned short* __restrict__ Whfx1, unsigned short* __restrict__ Wlfx1,
    unsigned short* __restrict__ Whfx2, unsigned short* __restrict__ Wlfx2,
    unsigned int* __restrict__ mx, int* __restrict__ bcur, int nbuck){
  __shared__ float wa[2][128];
  int layer = blockIdx.x;
  const float* W  = layer ? W2 : W1;
  const float* as = layer ? as2 : as1;
  const float* ad = layer ? ad2 : ad1;
  unsigned short* Whfx = layer ? Whfx2 : Whfx1;
  unsigned short* Wlfx = layer ? Wlfx2 : Wlfx1;
  int t = threadIdx.x;
  if (t < 2) mx[layer*2 + t] = 0u;
  if (layer == 0 && t < nbuck) bcur[t] = t * BCAP;

  // wa[which][row] = dot(W[row,:], a)
  int row = t & 127;
  const float* a = (t >> 7) ? ad : as;
  float s = 0.f;
  #pragma unroll 8
  for (int c = 0; c < 128; c += 4){
    float4 wv = *(const float4*)&W[row*128 + c];
    s += wv.x*a[c] + wv.y*a[c+1] + wv.z*a[c+2] + wv.w*a[c+3];
  }
  wa[t >> 7][row] = s;
  __syncthreads();

  int kc = t >> 6, lane = t & 63;
  int l15 = lane & 15, l4 = lane >> 4;
  unsigned short hh[8], ll[8];
  #pragma unroll
  for (int e = 0; e < 8; ++e){
    int k = (kc*4 + l4)*8 + e;
    float v = (l15 == 0) ? wa[0][k] : ((l15 == 1) ? wa[1][k] : 0.f);
    unsigned short h = bf16_rn(v);
    hh[e] = h;
    ll[e] = bf16_rn(v - __uint_as_float(((unsigned)h) << 16));
  }
  #pragma unroll
  for (int e = 0; e < 8; ++e){ Whfx[t*8 + e] = hh[e]; Wlfx[t*8 + e] = ll[e]; }
}

// ---------------- MFMA bf16 GEMM (2-term) + MFMA logits + per-BLOCK global max ----------------
// Hb stored in PERMUTED row layout: ushort p of row r holds H[r][(p&7)*16 + (p>>3)].
__global__ __launch_bounds__(256) void gemm_al_kernel(const float* __restrict__ X,
    const unsigned short* __restrict__ Whf, const unsigned short* __restrict__ Wlf,
    const unsigned short* __restrict__ Whfx, const unsigned short* __restrict__ Wlfx,
    unsigned short* __restrict__ Hb, float* __restrict__ ALs, float* __restrict__ ALd,
    unsigned int* __restrict__ mx, int n)
{
  __shared__ unsigned short Xh[128*128];   // 32 KB
  __shared__ float redS[4], redD[4];
  int tid  = threadIdx.x;
  int lane = tid & 63;
  int wave = tid >> 6;
  int row0 = blockIdx.x * 128;
  int c4   = tid & 31;

  #pragma unroll 4
  for (int it = 0; it < 16; ++it){
    int f  = it*256 + tid;
    int r  = f >> 5;
    float4 v = make_float4(0.f,0.f,0.f,0.f);
    int gr = row0 + r;
    if (gr < n) v = ((const float4*)(X + (size_t)gr*D))[c4];
    unsigned short h0 = bf16_rn(v.x);
    unsigned short h1 = bf16_rn(v.y);
    unsigned short h2 = bf16_rn(v.z);
    unsigned short h3 = bf16_rn(v.w);
    int g   = (c4 >> 1) ^ (r & 7);
    int idx = r*128 + (g << 3) + ((c4 & 1) << 2);
    *(uint2*)&Xh[idx] = make_uint2((unsigned)h0 | ((unsigned)h1<<16),
                                   (unsigned)h2 | ((unsigned)h3<<16));
  }
  __syncthreads();

  int l15 = lane & 15;
  int l4  = lane >> 4;

  f32x4 acc[2][8];
  f32x4 acc2[2];
  #pragma unroll
  for (int rf = 0; rf < 2; ++rf){
    #pragma unroll
    for (int cf = 0; cf < 8; ++cf)
      acc[rf][cf] = (f32x4){0.f, 0.f, 0.f, 0.f};
    acc2[rf] = (f32x4){0.f, 0.f, 0.f, 0.f};
  }

  #pragma unroll
  for (int kc = 0; kc < 4; ++kc){
    int g = kc*4 + l4;
    bf16x8 ah[2];
    #pragma unroll
    for (int rf = 0; rf < 2; ++rf){
      int r   = wave*32 + rf*16 + l15;
      int idx = r*128 + ((g ^ (r & 7)) << 3);
      ah[rf] = *(const bf16x8*)&Xh[idx];
    }
    #pragma unroll
    for (int cf = 0; cf < 8; ++cf){
      int foff = ((kc*8 + cf) << 9) + (lane << 3);
      bf16x8 bh = *(const bf16x8*)&Whf[foff];
      bf16x8 bl = *(const bf16x8*)&Wlf[foff];
      #pragma unroll
      for (int rf = 0; rf < 2; ++rf){
        acc[rf][cf] = __builtin_amdgcn_mfma_f32_16x16x32_bf16(ah[rf], bh, acc[rf][cf], 0, 0, 0);
        acc[rf][cf] = __builtin_amdgcn_mfma_f32_16x16x32_bf16(ah[rf], bl, acc[rf][cf], 0, 0, 0);
      }
    }
    {
      int foffx = ((kc << 6) + lane) << 3;
      bf16x8 bhx = *(const bf16x8*)&Whfx[foffx];
      bf16x8 blx = *(const bf16x8*)&Wlfx[foffx];
      #pragma unroll
      for (int rf = 0; rf < 2; ++rf){
        acc2[rf] = __builtin_amdgcn_mfma_f32_16x16x32_bf16(ah[rf], bhx, acc2[rf], 0, 0, 0);
        acc2[rf] = __builtin_amdgcn_mfma_f32_16x16x32_bf16(ah[rf], blx, acc2[rf], 0, 0, 0);
      }
    }
  }

  float ms = -3e38f, md = -3e38f;
  #pragma unroll
  for (int rf = 0; rf < 2; ++rf){
    #pragma unroll
    for (int reg = 0; reg < 4; ++reg){
      int gr = row0 + wave*32 + rf*16 + l4*4 + reg;   // C/D: row=(lane>>4)*4+reg
      if (gr < n){
        unsigned int p0 = (unsigned)bf16_rn(acc[rf][0][reg]) | ((unsigned)bf16_rn(acc[rf][1][reg]) << 16);
        unsigned int p1 = (unsigned)bf16_rn(acc[rf][2][reg]) | ((unsigned)bf16_rn(acc[rf][3][reg]) << 16);
        unsigned int p2 = (unsigned)bf16_rn(acc[rf][4][reg]) | ((unsigned)bf16_rn(acc[rf][5][reg]) << 16);
        unsigned int p3 = (unsigned)bf16_rn(acc[rf][6][reg]) | ((unsigned)bf16_rn(acc[rf][7][reg]) << 16);
        ((uint4*)(Hb + (size_t)gr*D))[l15] = make_uint4(p0, p1, p2, p3);
        if (l15 == 0){      ALs[gr] = acc2[rf][reg]; ms = fmaxf(ms, acc2[rf][reg]); }
        else if (l15 == 1){ ALd[gr] = acc2[rf][reg]; md = fmaxf(md, acc2[rf][reg]); }
      }
    }
  }
  // block-level max reduce -> ONE atomic pair per block (avoids atomic hotspot)
  #pragma unroll
  for (int off = 32; off >= 1; off >>= 1){
    ms = fmaxf(ms, __shfl_xor(ms, off));
    md = fmaxf(md, __shfl_xor(md, off));
  }
  if (lane == 0){ redS[wave] = ms; redD[wave] = md; }
  __syncthreads();
  if (tid == 0){
    float a = fmaxf(fmaxf(redS[0], redS[1]), fmaxf(redS[2], redS[3]));
    float b = fmaxf(fmaxf(redD[0], redD[1]), fmaxf(redD[2], redD[3]));
    atomicMax(&mx[0], enc_f(a));
    atomicMax(&mx[1], enc_f(b));
  }
}

// ---------------- fused softmax + weighted gather aggregation ----------------
// Global-bound softmax (M >= all logits). Per chunk: lane q computes w for edge
// beg+q, stages s/w to wave-private LDS; gather loop reads them with uniform
// ds_read (broadcast). z accumulates per-lane.
__global__ __launch_bounds__(256) void agg_kernel(const unsigned short* __restrict__ Hb,
    const float* __restrict__ ALs, const float* __restrict__ ALd,
    const unsigned int* __restrict__ mx,
    const int2* __restrict__ rowrange, const int* __restrict__ colb,
    const float* __restrict__ bias, float* __restrict__ out, int n)
{
  __shared__ unsigned int sArr[256];
  __shared__ float wArr[256];
  int gtid = blockIdx.x*blockDim.x + threadIdx.x;
  int node = gtid >> 6;
  int lane = threadIdx.x & 63;
  int wbase = threadIdx.x & 192;         // wave slice base
  if (node >= n) return;

  float M = lrelu(dec_f(mx[0]) + dec_f(mx[1]));   // upper bound on all edge logits

  int2 rr = rowrange[node];
  int beg = rr.x, end = rr.y;
  float ald = ALd[node];
  float ws = __expf(lrelu(ALs[node] + ald) - M);  // self-loop weight

  const unsigned int* H2 = (const unsigned int*)Hb;
  unsigned int us = H2[(unsigned)(node*64 + lane)];
  float2 acc; acc.x = ws * bf16_lo_f(us); acc.y = ws * bf16_hi_f(us);
  float zl = 0.f;

  for (int c = beg; c < end; c += 64){
    int j = c + lane;
    bool valid = j < end;
    int s_l = valid ? colb[j] : 0;
    float w_l = valid ? __expf(lrelu(ALs[s_l] + ald) - M) : 0.f;
    zl += w_l;

    sArr[threadIdx.x] = (unsigned)s_l;
    wArr[threadIdx.x] = w_l;

    int cnt = end - c; if (cnt > 64) cnt = 64;
    int q = 0;
    for (; q + 8 <= cnt; q += 8){
      unsigned int ss[8]; float ww[8]; unsigned int u[8];
      #pragma unroll
      for (int p = 0; p < 8; ++p){ ss[p] = sArr[wbase + q + p]; ww[p] = wArr[wbase + q + p]; }
      #pragma unroll
      for (int p = 0; p < 8; ++p) u[p] = H2[(unsigned)(ss[p]*64u + lane)];
      #pragma unroll
      for (int p = 0; p < 8; ++p){
        acc.x += ww[p]*bf16_lo_f(u[p]);
        acc.y += ww[p]*bf16_hi_f(u[p]);
      }
    }
    for (; q < cnt; ++q){
      unsigned int u = H2[(unsigned)(sArr[wbase + q]*64u + lane)];
      float w = wArr[wbase + q];
      acc.x += w*bf16_lo_f(u); acc.y += w*bf16_hi_f(u);
    }
  }

  #pragma unroll
  for (int off = 32; off >= 1; off >>= 1) zl += __shfl_xor(zl, off);
  float zi = 1.f / (zl + ws);
  acc.x *= zi; acc.y *= zi;

  // permuted -> standard: lane t needs cols 2t (v0) and 2t+1 (v1)
  int q0 = (lane >> 4) + ((lane & 7) << 3);
  int q1 = q0 + 4;
  int hsel = (lane >> 3) & 1;
  float x0 = __shfl(acc.x, q0), y0 = __shfl(acc.y, q0);
  float x1 = __shfl(acc.x, q1), y1 = __shfl(acc.y, q1);
  float v0 = hsel ? y0 : x0;
  float v1 = hsel ? y1 : x1;

  float2 b2 = ((const float2*)bias)[lane];
  ((float2*)out)[(size_t)node*64 + lane] = make_float2(v0 + b2.x, v1 + b2.y);
}

// ---------------- launch ----------------
extern "C" void kernel_launch(void* const* d_in, const int* in_sizes, int n_in,
                              void* d_out, int out_size, void* d_ws, size_t ws_size,
                              hipStream_t stream)
{
  const float* x   = (const float*)d_in[0];
  const int*   ei  = (const int*)  d_in[1];
  const float* W1  = (const float*)d_in[2];
  const float* as1 = (const float*)d_in[3];
  const float* ad1 = (const float*)d_in[4];
  const float* b1  = (const float*)d_in[5];
  const float* W2  = (const float*)d_in[6];
  const float* as2 = (const float*)d_in[7];
  const float* ad2 = (const float*)d_in[8];
  const float* b2  = (const float*)d_in[9];

  int n = in_sizes[0] / D;
  int E = in_sizes[1] / 2;
  const int* src = ei;
  const int* dst = ei + E;
  int nbuck = (n + BSZ - 1) >> BSH;

  // workspace layout (256B-aligned chunks)
  char* base = (char*)d_ws;
  size_t off = 0;
  auto alloc = [&](size_t bytes) -> char* {
    char* p = base + off;
    off = (off + bytes + 255) & ~(size_t)255;
    return p;
  };
  unsigned short* hb = (unsigned short*)alloc((size_t)n*D*2);
  float* als    = (float*)alloc((size_t)n*4);
  float* ald    = (float*)alloc((size_t)n*4);
  int2* rowrange = (int2*)alloc((size_t)n*8);
  int* bcur     = (int*)alloc(256*4);
  unsigned int* mx = (unsigned int*)alloc(4*4);   // mx1 = mx+0, mx2 = mx+2
  unsigned short* whf1 = (unsigned short*)alloc(16384*2);
  unsigned short* wlf1 = (unsigned short*)alloc(16384*2);
  unsigned short* whf2 = (unsigned short*)alloc(16384*2);
  unsigned short* wlf2 = (unsigned short*)alloc(16384*2);
  unsigned short* whfx1 = (unsigned short*)alloc(2048*2);
  unsigned short* wlfx1 = (unsigned short*)alloc(2048*2);
  unsigned short* whfx2 = (unsigned short*)alloc(2048*2);
  unsigned short* wlfx2 = (unsigned short*)alloc(2048*2);
  unsigned int* ebuf = (unsigned int*)alloc((size_t)nbuck*BCAP*4);
  int* colb = (int*)alloc((size_t)nbuck*BCAP*4);

  float* out = (float*)d_out;

  // prep: 2 dispatches (init duties folded in)
  wsplit_kernel<<<128, 256, 0, stream>>>(W1, W2, whf1, wlf1, whf2, wlf2);
  wafrag_kernel<<<2, 256, 0, stream>>>(W1, W2, as1, ad1, as2, ad2,
                                       whfx1, wlfx1, whfx2, wlfx2, mx, bcur, nbuck);

  // CSR build: 2 dispatches
  int sc_blocks = (E + SC_CHUNK - 1) / SC_CHUNK;
  bucket_scatter_kernel<<<sc_blocks, 1024, 0, stream>>>(src, dst, E, bcur, ebuf, nbuck);
  bucket_csr_kernel    <<<nbuck, 256, 0, stream>>>(ebuf, bcur, rowrange, colb, n, nbuck);

  int ntiles = (n + 127)/128;
  int aggblocks = (int)(((size_t)n*64 + 255)/256);

  gemm_al_kernel<<<ntiles, 256, 0, stream>>>(x,  whf1, wlf1, whfx1, wlfx1, hb, als, ald, mx,   n);
  agg_kernel    <<<aggblocks, 256, 0, stream>>>(hb, als, ald, mx,   rowrange, colb, b1, out, n);
  gemm_al_kernel<<<ntiles, 256, 0, stream>>>(out, whf2, wlf2, whfx2, wlfx2, hb, als, ald, mx+2, n);
  agg_kernel    <<<aggblocks, 256, 0, stream>>>(hb, als, ald, mx+2, rowrange, colb, b2, out, n);
}